// Round 2
// baseline (352.858 us; speedup 1.0000x reference)
//
#include <hip/hip_runtime.h>

typedef unsigned int u32;
typedef unsigned short u16;
typedef float f32x4 __attribute__((ext_vector_type(4)));
typedef u32 u32x4 __attribute__((ext_vector_type(4)));
typedef short s16x8 __attribute__((ext_vector_type(8)));

__device__ __forceinline__ u32 f2bf(float f) {
  u32 x = __builtin_bit_cast(u32, f);
  return (x + 0x7FFFu + ((x >> 16) & 1u)) >> 16;   // RNE f32 -> bf16 bits
}
__device__ __forceinline__ u32 pack2(float lo, float hi) {
  return f2bf(lo) | (f2bf(hi) << 16);
}
__device__ __forceinline__ float bfu2f(u16 u) {
  u32 x = ((u32)u) << 16;
  return __builtin_bit_cast(float, x);
}
__device__ __forceinline__ u32x4 mk8(const float* v) {
  u32x4 u;
  u.x = pack2(v[0], v[1]); u.y = pack2(v[2], v[3]);
  u.z = pack2(v[4], v[5]); u.w = pack2(v[6], v[7]);
  return u;
}
// D = A*B + D, 16x16x32 bf16 (builtin: compiler handles MFMA hazards).
// A/B fragments use the same (lane-group, elem)->k map, so any consistent
// K-slot pairing on both operands is valid. D: col=lane&15, row=(lane>>4)*4+r.
__device__ __forceinline__ void mfma16(f32x4& acc, u32x4 a, u32x4 b) {
  acc = __builtin_amdgcn_mfma_f32_16x16x32_bf16(
      __builtin_bit_cast(s16x8, a), __builtin_bit_cast(s16x8, b), acc, 0, 0, 0);
}

// ---------------------------------------------------------------------------
// K0: gather x (64,3,128,128) into phi1[p][s][f][b], f in [0,96): [x, 1-x]
// ---------------------------------------------------------------------------
__global__ __launch_bounds__(256) void k_gather1(const float* __restrict__ x,
                                                 float* __restrict__ phi1) {
  __shared__ float tile[64][65];
  const int t = threadIdx.x;
  const int base = blockIdx.x * 64;
  const int lb = t & 63;
  {
    const int flat = base + lb;
    const int c = flat >> 14;
    const int r1 = flat & 16383;
    const int h1 = r1 >> 12;
    const int r2 = r1 & 4095;
    const int w1 = r2 >> 10;
    const int r3 = r2 & 1023;
    const int h2 = r3 >> 5;
    const int w2 = r3 & 31;
    const int xoff = c * 16384 + h1 * 4096 + h2 * 128 + w1 * 32 + w2;
    for (int b = t >> 6; b < 64; b += 4)
      tile[lb][b] = x[b * 49152 + xoff];
  }
  __syncthreads();
  for (int q = t >> 6; q < 64; q += 4) {
    const int flat = base + q;
    const int a = flat / 1536;
    const int rem = flat % 1536;
    const int e = rem / 48, gg = rem % 48;
    const int e1 = e >> 4, e2 = e & 15, g1 = gg >> 4, g2 = gg & 15;
    const int tt = a * 6 + e1 * 3 + g1;
    const int F = tt >> 2, Sx = tt & 3, Pp = e2 * 16 + g2;
    const float val = tile[q][lb];
    const int idx = ((Pp * 4 + Sx) * 96 + F) * 64 + lb;
    phi1[idx] = val;
    phi1[idx + 3072] = 1.0f - val;   // f+48
  }
}

// ---------------------------------------------------------------------------
// K1: level-1 fused vector-chain. One WG per patch p (256 WGs, 512 thr).
// ---------------------------------------------------------------------------
__global__ __launch_bounds__(512) void k_level1(const float* __restrict__ phi1,
                                                const float* __restrict__ cores1,
                                                const float* __restrict__ label1,
                                                float* __restrict__ y1raw) {
  __shared__ float phi_s[96 * 64];
  __shared__ float v_s[64 * 33];
  __shared__ float lab_s[32 * 32];   // [j][o]
  const int p = blockIdx.x;
  const int t = threadIdx.x;
  const int w = t >> 6, lane = t & 63;
  const int g = lane >> 4, l15 = lane & 15;
  const int jm = w & 1, bn = w >> 1;
  const int rowj = jm * 16 + l15;   // output column j (MFMA M-rows)
  const int colb = bn * 16 + l15;   // batch b (MFMA N-cols)
  const float* phip = phi1 + p * 24576;
  const float* Cp = cores1 + p * 393216;

  // load phi(s=0)
  {
    const float4* s4 = (const float4*)phip;
    float4* d4 = (float4*)phi_s;
#pragma unroll
    for (int k = 0; k < 3; ++k) d4[t + k * 512] = s4[t + k * 512];
  }
  __syncthreads();
  // site 0: v[b,j] = sum_f phi[b,f] * C[p,0,f,0,j]
  {
    f32x4 acc = {0.f, 0.f, 0.f, 0.f};
    const float* A0 = Cp + rowj;
#pragma unroll
    for (int ks = 0; ks < 3; ++ks) {
      float av[8], bv[8];
#pragma unroll
      for (int e = 0; e < 8; ++e) {
        const int f = ks * 32 + g * 8 + e;
        av[e] = A0[f * 1024];
        bv[e] = phi_s[f * 64 + colb];
      }
      mfma16(acc, mk8(av), mk8(bv));
    }
#pragma unroll
    for (int r = 0; r < 4; ++r) v_s[colb * 33 + jm * 16 + g * 4 + r] = acc[r];
  }
  // sites 1..3: v[b,j] = sum_{f,i} phi[b,f]*v[b,i]*C[p,s,f,i,j]
  for (int s = 1; s < 4; ++s) {
    __syncthreads();   // v_s ready
    float v8[8];
#pragma unroll
    for (int e = 0; e < 8; ++e) v8[e] = v_s[colb * 33 + g * 8 + e];
    {
      const float4* s4 = (const float4*)(phip + s * 6144);
      float4* d4 = (float4*)phi_s;
#pragma unroll
      for (int k = 0; k < 3; ++k) d4[t + k * 512] = s4[t + k * 512];
    }
    __syncthreads();   // phi ready; all v8 reads done -> later v_s writes safe
    const float* A0 = Cp + s * 98304 + g * 256 + rowj;
    float pf0[8], pf1[8], pf2[8];
#pragma unroll
    for (int e = 0; e < 8; ++e) pf0[e] = A0[e * 32];
#pragma unroll
    for (int e = 0; e < 8; ++e) pf1[e] = A0[1024 + e * 32];
#pragma unroll
    for (int e = 0; e < 8; ++e) pf2[e] = A0[2048 + e * 32];
    f32x4 acc = {0.f, 0.f, 0.f, 0.f};
    for (int f = 0; f < 96; f += 3) {
      {
        const float phf = phi_s[f * 64 + colb];
        float bv[8];
#pragma unroll
        for (int e = 0; e < 8; ++e) bv[e] = phf * v8[e];
        mfma16(acc, mk8(pf0), mk8(bv));
        if (f + 3 < 96) {
#pragma unroll
          for (int e = 0; e < 8; ++e) pf0[e] = A0[(f + 3) * 1024 + e * 32];
        }
      }
      {
        const float phf = phi_s[(f + 1) * 64 + colb];
        float bv[8];
#pragma unroll
        for (int e = 0; e < 8; ++e) bv[e] = phf * v8[e];
        mfma16(acc, mk8(pf1), mk8(bv));
        if (f + 4 < 96) {
#pragma unroll
          for (int e = 0; e < 8; ++e) pf1[e] = A0[(f + 4) * 1024 + e * 32];
        }
      }
      {
        const float phf = phi_s[(f + 2) * 64 + colb];
        float bv[8];
#pragma unroll
        for (int e = 0; e < 8; ++e) bv[e] = phf * v8[e];
        mfma16(acc, mk8(pf2), mk8(bv));
        if (f + 5 < 96) {
#pragma unroll
          for (int e = 0; e < 8; ++e) pf2[e] = A0[(f + 5) * 1024 + e * 32];
        }
      }
    }
#pragma unroll
    for (int r = 0; r < 4; ++r) v_s[colb * 33 + jm * 16 + g * 4 + r] = acc[r];
  }
  __syncthreads();
  // label contraction: y[b,o] = sum_j v[b,j] * label1[p,o,j,0]
  for (int i = t; i < 1024; i += 512)
    lab_s[(i & 31) * 32 + (i >> 5)] = label1[(p * 1024 + i) * 32];
  __syncthreads();
  {
    const int b = t & 63, og = t >> 6;
    float a[4] = {0.f, 0.f, 0.f, 0.f};
    for (int j = 0; j < 32; ++j) {
      const float vj = v_s[b * 33 + j];
#pragma unroll
      for (int r = 0; r < 4; ++r) a[r] += vj * lab_s[j * 32 + og * 4 + r];
    }
#pragma unroll
    for (int r = 0; r < 4; ++r)
      y1raw[((og * 4 + r) * 256 + p) * 64 + b] = a[r];
  }
}

// ---------------------------------------------------------------------------
// BatchNorm1d (training mode, biased var): layout [o][P][64], stats over P*64.
// ---------------------------------------------------------------------------
__global__ __launch_bounds__(256) void k_bn(const float* __restrict__ yin,
                                            float* __restrict__ yout,
                                            const float* __restrict__ gamma,
                                            const float* __restrict__ beta,
                                            int Pn) {
  __shared__ float red[256];
  const int o = blockIdx.x, t = threadIdx.x;
  const int N = Pn * 64;
  const float* src = yin + o * N;
  float* dst = yout + o * N;
  float s = 0.f;
  for (int i = t; i < N; i += 256) s += src[i];
  red[t] = s;
  __syncthreads();
  for (int k = 128; k > 0; k >>= 1) { if (t < k) red[t] += red[t + k]; __syncthreads(); }
  const float mean = red[0] / (float)N;
  __syncthreads();
  float s2 = 0.f;
  for (int i = t; i < N; i += 256) { const float d = src[i] - mean; s2 += d * d; }
  red[t] = s2;
  __syncthreads();
  for (int k = 128; k > 0; k >>= 1) { if (t < k) red[t] += red[t + k]; __syncthreads(); }
  const float var = red[0] / (float)N;
  const float sc = gamma[o] * rsqrtf(var + 1e-5f);
  const float sh = beta[o] - mean * sc;
  for (int i = t; i < N; i += 256) dst[i] = src[i] * sc + sh;
}

// ---------------------------------------------------------------------------
// Build site matrices (levels 2,3, final): mats[p][s-1][b][ij] (bf16) for s>=1,
// v0[p][b][j] for s==0 (row 0 only). GEMM M=64(b) x N=1024(ij) x K=64(f).
// ---------------------------------------------------------------------------
template <int LEVEL>
__global__ __launch_bounds__(512) void k_build(const float* __restrict__ yn,
                                               const float* __restrict__ cores,
                                               u16* __restrict__ mats,
                                               float* __restrict__ v0) {
  constexpr int S = (LEVEL == 0) ? 16 : 4;
  constexpr int NQ = (LEVEL == 2) ? 2 : 4;
  constexpr int NC = 1024 / NQ;
  constexpr int NTW = NC / 32;
  __shared__ float phi_s[64 * 64];
  const int bid = blockIdx.x;
  const int p = bid / (S * NQ);
  const int rs = bid % (S * NQ);
  const int s = rs / NQ, nq = rs % NQ;
  if (s == 0 && nq != 0) return;   // block-uniform early exit
  const int t = threadIdx.x;
  const int w = t >> 6, lane = t & 63;
  const int g = lane >> 4, l15 = lane & 15;
  for (int i = t; i < 2048; i += 512) {
    const int f = i >> 6, b = i & 63;
    int src;
    if (LEVEL == 2) {
      const int u = (s >> 1) * 8 + (p >> 3), vv = (s & 1) * 8 + (p & 7);
      src = (f * 256 + u * 16 + vv) * 64 + b;
    } else if (LEVEL == 3) {
      const int u = (s >> 1) * 4 + (p >> 2), vv = (s & 1) * 4 + (p & 3);
      src = (f * 64 + u * 8 + vv) * 64 + b;
    } else {
      src = (f * 16 + s) * 64 + b;
    }
    const float val = yn[src];
    phi_s[f * 64 + b] = val;
    phi_s[(f + 32) * 64 + b] = 1.0f - val;
  }
  __syncthreads();
  const float* Cb = cores + (p * S + s) * 65536;
  const int m = w & 3, nh = w >> 2;
  const int rowb = m * 16 + l15;
  float av[8];
#pragma unroll
  for (int e = 0; e < 8; ++e) av[e] = phi_s[(g * 8 + e) * 64 + rowb];
  const u32x4 afr0 = mk8(av);
#pragma unroll
  for (int e = 0; e < 8; ++e) av[e] = phi_s[(32 + g * 8 + e) * 64 + rowb];
  const u32x4 afr1 = mk8(av);
  if (s == 0) {
    const int col = nh * 16 + l15;   // j in [0,32)
    f32x4 acc = {0.f, 0.f, 0.f, 0.f};
    float bv[8];
#pragma unroll
    for (int e = 0; e < 8; ++e) bv[e] = Cb[(g * 8 + e) * 1024 + col];  // C[f][0][j]
    mfma16(acc, afr0, mk8(bv));
#pragma unroll
    for (int e = 0; e < 8; ++e) bv[e] = Cb[(32 + g * 8 + e) * 1024 + col];
    mfma16(acc, afr1, mk8(bv));
#pragma unroll
    for (int r = 0; r < 4; ++r)
      v0[(p * 64 + m * 16 + g * 4 + r) * 32 + col] = acc[r];
  } else {
#pragma unroll 2
    for (int nt = 0; nt < NTW; ++nt) {
      const int col = nq * NC + (nh * NTW + nt) * 16 + l15;   // ij
      f32x4 acc = {0.f, 0.f, 0.f, 0.f};
      float bv[8];
#pragma unroll
      for (int e = 0; e < 8; ++e) bv[e] = Cb[(g * 8 + e) * 1024 + col];
      mfma16(acc, afr0, mk8(bv));
#pragma unroll
      for (int e = 0; e < 8; ++e) bv[e] = Cb[(32 + g * 8 + e) * 1024 + col];
      mfma16(acc, afr1, mk8(bv));
      u16* mp = mats + (((size_t)p * (S - 1) + (s - 1)) * 64 + m * 16 + g * 4) * 1024 + col;
#pragma unroll
      for (int r = 0; r < 4; ++r) mp[r * 1024] = (u16)f2bf(acc[r]);
    }
  }
}

// ---------------------------------------------------------------------------
// Chain (levels 2,3): v0 -> xM1 xM2 xM3 -> label -> yraw[o][P][b]. Wave per b.
// ---------------------------------------------------------------------------
template <int LEVEL>
__global__ __launch_bounds__(256) void k_chain(const float* __restrict__ v0,
                                               const u16* __restrict__ mats,
                                               const float* __restrict__ label,
                                               float* __restrict__ yraw) {
  constexpr int P = (LEVEL == 2) ? 64 : 16;
  __shared__ float lab_s[1024];   // [j][o]
  const int p = blockIdx.x >> 4, bq = blockIdx.x & 15;
  const int t = threadIdx.x, w = t >> 6, lane = t & 63;
  for (int i = t; i < 1024; i += 256)
    lab_s[(i & 31) * 32 + (i >> 5)] = label[(p * 1024 + i) * 32];
  __syncthreads();
  const int b = bq * 4 + w, j = lane & 31;
  float v = v0[(p * 64 + b) * 32 + j];
#pragma unroll
  for (int s1 = 0; s1 < 3; ++s1) {
    const u16* M = mats + (((size_t)p * 3 + s1) * 64 + b) * 1024;
    float acc = 0.f;
#pragma unroll
    for (int i = 0; i < 32; ++i)
      acc += __shfl(v, i, 64) * bfu2f(M[i * 32 + j]);
    v = acc;
  }
  float out = 0.f;
#pragma unroll
  for (int jj = 0; jj < 32; ++jj)
    out += __shfl(v, jj, 64) * lab_s[jj * 32 + j];
  if (lane < 32) yraw[(j * P + p) * 64 + b] = out;
}

// ---------------------------------------------------------------------------
// Final chain: 15 site matrices then labelF dot. Wave per b.
// ---------------------------------------------------------------------------
__global__ __launch_bounds__(256) void k_chainF(const float* __restrict__ v0,
                                                const u16* __restrict__ mats,
                                                const float* __restrict__ labelF,
                                                float* __restrict__ out) {
  const int t = threadIdx.x, w = t >> 6, lane = t & 63;
  const int b = blockIdx.x * 4 + w, j = lane & 31;
  float v = v0[b * 32 + j];
  for (int s1 = 0; s1 < 15; ++s1) {
    const u16* M = mats + ((size_t)s1 * 64 + b) * 1024;
    float acc = 0.f;
#pragma unroll
    for (int i = 0; i < 32; ++i)
      acc += __shfl(v, i, 64) * bfu2f(M[i * 32 + j]);
    v = acc;
  }
  float r = v * labelF[j * 32];
#pragma unroll
  for (int off = 16; off > 0; off >>= 1) r += __shfl_xor(r, off, 64);
  if (lane == 0) out[b] = r;
}

// ---------------------------------------------------------------------------
extern "C" void kernel_launch(void* const* d_in, const int* in_sizes, int n_in,
                              void* d_out, int out_size, void* d_ws, size_t ws_size,
                              hipStream_t stream) {
  (void)in_sizes; (void)n_in; (void)out_size; (void)ws_size;
  const float* x      = (const float*)d_in[0];
  const float* cores1 = (const float*)d_in[1];
  const float* label1 = (const float*)d_in[2];
  const float* g1     = (const float*)d_in[3];
  const float* b1     = (const float*)d_in[4];
  const float* cores2 = (const float*)d_in[5];
  const float* label2 = (const float*)d_in[6];
  const float* g2     = (const float*)d_in[7];
  const float* b2     = (const float*)d_in[8];
  const float* cores3 = (const float*)d_in[9];
  const float* label3 = (const float*)d_in[10];
  const float* g3     = (const float*)d_in[11];
  const float* b3     = (const float*)d_in[12];
  const float* coresF = (const float*)d_in[13];
  const float* labelF = (const float*)d_in[14];

  char* wsb = (char*)d_ws;
  size_t off = 0;
  auto alloc = [&](size_t bytes) -> char* {
    char* r = wsb + off;
    off += (bytes + 255) & ~(size_t)255;
    return r;
  };
  // Region 0: phi1 (live: k_gather1 -> k_level1) and mats2 (live: k_build<2>
  // -> k_chain<2>) have disjoint lifetimes and identical size (24 MB): alias.
  char* region0 = alloc(6291456ull * 4);
  float* phi1  = (float*)region0;                 // [256][4][96][64]
  u16*   mats2 = (u16*)region0;                   // [64][3][64][1024]
  float* y1raw = (float*)alloc(524288ull * 4);    // [32][256][64]
  float* y1n   = (float*)alloc(524288ull * 4);
  float* v02   = (float*)alloc(131072ull * 4);    // [64][64][32]
  float* y2raw = (float*)alloc(131072ull * 4);    // [32][64][64]
  float* y2n   = (float*)alloc(131072ull * 4);
  float* v03   = (float*)alloc(32768ull * 4);     // [16][64][32]
  u16*   mats3 = (u16*)  alloc(3145728ull * 2);   // [16][3][64][1024]
  float* y3raw = (float*)alloc(32768ull * 4);     // [32][16][64]
  float* y3n   = (float*)alloc(32768ull * 4);
  float* v0F   = (float*)alloc(2048ull * 4);      // [64][32]
  u16*   matsF = (u16*)  alloc(983040ull * 2);    // [15][64][1024]

  k_gather1<<<768, 256, 0, stream>>>(x, phi1);
  k_level1<<<256, 512, 0, stream>>>(phi1, cores1, label1, y1raw);
  k_bn<<<32, 256, 0, stream>>>(y1raw, y1n, g1, b1, 256);
  k_build<2><<<512, 512, 0, stream>>>(y1n, cores2, mats2, v02);
  k_chain<2><<<1024, 256, 0, stream>>>(v02, mats2, label2, y2raw);
  k_bn<<<32, 256, 0, stream>>>(y2raw, y2n, g2, b2, 64);
  k_build<3><<<256, 512, 0, stream>>>(y2n, cores3, mats3, v03);
  k_chain<3><<<256, 256, 0, stream>>>(v03, mats3, label3, y3raw);
  k_bn<<<32, 256, 0, stream>>>(y3raw, y3n, g3, b3, 16);
  k_build<0><<<64, 512, 0, stream>>>(y3n, coresF, matsF, v0F);
  k_chainF<<<16, 256, 0, stream>>>(v0F, matsF, labelF, (float*)d_out);
}

// Round 3
// 279.067 us; speedup vs baseline: 1.2644x; 1.2644x over previous
//
#include <hip/hip_runtime.h>

typedef unsigned int u32;
typedef unsigned short u16;
typedef float f32x4 __attribute__((ext_vector_type(4)));
typedef u32 u32x4 __attribute__((ext_vector_type(4)));
typedef short s16x8 __attribute__((ext_vector_type(8)));

__device__ __forceinline__ u32 f2bf(float f) {
  u32 x = __builtin_bit_cast(u32, f);
  return (x + 0x7FFFu + ((x >> 16) & 1u)) >> 16;   // RNE f32 -> bf16 bits
}
__device__ __forceinline__ float bfu2f(u16 u) {
  u32 x = ((u32)u) << 16;
  return __builtin_bit_cast(float, x);
}
// single-instruction RNE pack of two f32 -> bf16x2 (VALU asm is hazard-safe;
// only raw MFMA asm bypassed hazard handling in round 1)
__device__ __forceinline__ u32 cvtpk(float lo, float hi) {
  u32 r;
  asm("v_cvt_pk_bf16_f32 %0, %1, %2" : "=v"(r) : "v"(lo), "v"(hi));
  return r;
}
__device__ __forceinline__ u32x4 mk8(const float* v) {
  u32x4 u;
  u.x = cvtpk(v[0], v[1]); u.y = cvtpk(v[2], v[3]);
  u.z = cvtpk(v[4], v[5]); u.w = cvtpk(v[6], v[7]);
  return u;
}
// D = A*B + D, 16x16x32 bf16 builtin. D: col=lane&15, row=(lane>>4)*4+r.
__device__ __forceinline__ void mfma16(f32x4& acc, u32x4 a, u32x4 b) {
  acc = __builtin_amdgcn_mfma_f32_16x16x32_bf16(
      __builtin_bit_cast(s16x8, a), __builtin_bit_cast(s16x8, b), acc, 0, 0, 0);
}

// ---------------------------------------------------------------------------
// K0: gather x (64,3,128,128) into phi1[p][s][f][b], f in [0,96): [x, 1-x]
// ---------------------------------------------------------------------------
__global__ __launch_bounds__(256) void k_gather1(const float* __restrict__ x,
                                                 float* __restrict__ phi1) {
  __shared__ float tile[64][65];
  const int t = threadIdx.x;
  const int base = blockIdx.x * 64;
  const int lb = t & 63;
  {
    const int flat = base + lb;
    const int c = flat >> 14;
    const int r1 = flat & 16383;
    const int h1 = r1 >> 12;
    const int r2 = r1 & 4095;
    const int w1 = r2 >> 10;
    const int r3 = r2 & 1023;
    const int h2 = r3 >> 5;
    const int w2 = r3 & 31;
    const int xoff = c * 16384 + h1 * 4096 + h2 * 128 + w1 * 32 + w2;
    for (int b = t >> 6; b < 64; b += 4)
      tile[lb][b] = x[b * 49152 + xoff];
  }
  __syncthreads();
  for (int q = t >> 6; q < 64; q += 4) {
    const int flat = base + q;
    const int a = flat / 1536;
    const int rem = flat % 1536;
    const int e = rem / 48, gg = rem % 48;
    const int e1 = e >> 4, e2 = e & 15, g1 = gg >> 4, g2 = gg & 15;
    const int tt = a * 6 + e1 * 3 + g1;
    const int F = tt >> 2, Sx = tt & 3, Pp = e2 * 16 + g2;
    const float val = tile[q][lb];
    const int idx = ((Pp * 4 + Sx) * 96 + F) * 64 + lb;
    phi1[idx] = val;
    phi1[idx + 3072] = 1.0f - val;   // f+48
  }
}

// ---------------------------------------------------------------------------
// K1: level-1 fused vector-chain. One WG per patch p (256 WGs, 512 thr).
// Wave (jm=w&1, fq=w>>1): private f-slice [fq*24, fq*24+24), row-half jm,
// all 4 batch col-blocks. No redundant A loads; 6-deep prefetch ring.
// Partial accumulators reduced via padded LDS per site.
// ---------------------------------------------------------------------------
__global__ __launch_bounds__(512) void k_level1(const float* __restrict__ phi1,
                                                const float* __restrict__ cores1,
                                                const float* __restrict__ label1,
                                                float* __restrict__ y1raw) {
  __shared__ float phi_s[96 * 64];          // 24 KB
  __shared__ float v_s[64 * 33];            // 8.4 KB
  __shared__ float red_s[8 * 4 * 16 * 17];  // 34.8 KB, +17 pad
  __shared__ float lab_s[1024];             // 4 KB
  const int p = blockIdx.x, t = threadIdx.x;
  const int w = t >> 6, lane = t & 63, g = lane >> 4, l15 = lane & 15;
  const int jm = w & 1, fq = w >> 1;
  const float* phip = phi1 + p * 24576;
  const float* Cp = cores1 + p * 393216;

  // stage phi(site 0)
  {
    const float4* s4 = (const float4*)phip;
    float4* d4 = (float4*)phi_s;
#pragma unroll
    for (int k = 0; k < 3; ++k) d4[t + k * 512] = s4[t + k * 512];
  }
  __syncthreads();
  // site 0: v[b,j] = sum_f phi[b,f] * C[p,0,f,0,j]  (4x redundant loads, 12KB, L1-shared)
  {
    const int rowj = jm * 16 + l15, colb = fq * 16 + l15;
    f32x4 acc = {0.f, 0.f, 0.f, 0.f};
    const float* A0 = Cp + rowj;
#pragma unroll
    for (int ks = 0; ks < 3; ++ks) {
      float av[8], bv[8];
#pragma unroll
      for (int e = 0; e < 8; ++e) {
        const int f = ks * 32 + g * 8 + e;
        av[e] = A0[f * 1024];
        bv[e] = phi_s[f * 64 + colb];
      }
      mfma16(acc, mk8(av), mk8(bv));
    }
#pragma unroll
    for (int r = 0; r < 4; ++r) v_s[colb * 33 + jm * 16 + g * 4 + r] = acc[r];
  }
  // sites 1..3
  for (int s = 1; s < 4; ++s) {
    __syncthreads();   // v_s complete; all phi reads of previous site done
    float v8[4][8];
#pragma unroll
    for (int n = 0; n < 4; ++n)
#pragma unroll
      for (int e = 0; e < 8; ++e)
        v8[n][e] = v_s[(n * 16 + l15) * 33 + g * 8 + e];
    {
      const float4* s4 = (const float4*)(phip + s * 6144);
      float4* d4 = (float4*)phi_s;
#pragma unroll
      for (int k = 0; k < 3; ++k) d4[t + k * 512] = s4[t + k * 512];
    }
    // A(f,e) = As[f*1024 + e*32] = C[p][s][fq*24+f][i=g*8+e][j=jm*16+l15]
    const float* As = Cp + s * 98304 + fq * 24576 + g * 256 + jm * 16 + l15;
    float pf[6][8];
#pragma unroll
    for (int fi = 0; fi < 6; ++fi)
#pragma unroll
      for (int e = 0; e < 8; ++e) pf[fi][e] = As[fi * 1024 + e * 32];
    __syncthreads();   // phi ready
    f32x4 acc[4];
#pragma unroll
    for (int n = 0; n < 4; ++n) acc[n] = (f32x4){0.f, 0.f, 0.f, 0.f};
#pragma unroll
    for (int fo = 0; fo < 4; ++fo) {
#pragma unroll
      for (int fi = 0; fi < 6; ++fi) {
        const int f = fo * 6 + fi;
        const u32x4 afr = mk8(pf[fi]);
        if (f + 6 < 24) {
#pragma unroll
          for (int e = 0; e < 8; ++e) pf[fi][e] = As[(f + 6) * 1024 + e * 32];
        }
#pragma unroll
        for (int n = 0; n < 4; ++n) {
          const float phf = phi_s[(fq * 24 + f) * 64 + n * 16 + l15];
          float bv[8];
#pragma unroll
          for (int e = 0; e < 8; ++e) bv[e] = phf * v8[n][e];
          mfma16(acc[n], afr, mk8(bv));
        }
      }
    }
#pragma unroll
    for (int n = 0; n < 4; ++n)
#pragma unroll
      for (int r = 0; r < 4; ++r)
        red_s[((w * 4 + n) * 16 + g * 4 + r) * 17 + l15] = acc[n][r];
    __syncthreads();
    // v[b][j] = sum over fq-partials: waves w = (j>>4) + 2*fq
    for (int i = t; i < 2048; i += 512) {
      const int b = i >> 5, j = i & 31;
      const int n = b >> 4, lb = b & 15, jj = j >> 4, row = j & 15;
      const float sum = red_s[(((jj)*4 + n) * 16 + row) * 17 + lb]
                      + red_s[(((jj + 2) * 4 + n) * 16 + row) * 17 + lb]
                      + red_s[(((jj + 4) * 4 + n) * 16 + row) * 17 + lb]
                      + red_s[(((jj + 6) * 4 + n) * 16 + row) * 17 + lb];
      v_s[b * 33 + j] = sum;
    }
  }
  __syncthreads();
  // label contraction: y[b,o] = sum_j v[b,j] * label1[p,o,j,0]
  for (int i = t; i < 1024; i += 512)
    lab_s[(i & 31) * 32 + (i >> 5)] = label1[(p * 1024 + i) * 32];
  __syncthreads();
  {
    const int b = t & 63, og = t >> 6;
    float a[4] = {0.f, 0.f, 0.f, 0.f};
    for (int j = 0; j < 32; ++j) {
      const float vj = v_s[b * 33 + j];
#pragma unroll
      for (int r = 0; r < 4; ++r) a[r] += vj * lab_s[j * 32 + og * 4 + r];
    }
#pragma unroll
    for (int r = 0; r < 4; ++r)
      y1raw[((og * 4 + r) * 256 + p) * 64 + b] = a[r];
  }
}

// ---------------------------------------------------------------------------
// BN stats only (training mode, biased var): per-channel sc/sh. Normalize is
// folded into the consumer's gather (saves a full tensor round-trip).
// ---------------------------------------------------------------------------
__global__ __launch_bounds__(256) void k_bnstats(const float* __restrict__ yraw,
                                                 const float* __restrict__ gamma,
                                                 const float* __restrict__ beta,
                                                 float* __restrict__ scsh,
                                                 int Pn) {
  __shared__ float red[256];
  const int o = blockIdx.x, t = threadIdx.x;
  const int N = Pn * 64;
  const float* src = yraw + o * N;
  float s = 0.f;
  for (int i = t; i < N; i += 256) s += src[i];
  red[t] = s;
  __syncthreads();
  for (int k = 128; k > 0; k >>= 1) { if (t < k) red[t] += red[t + k]; __syncthreads(); }
  const float mean = red[0] / (float)N;
  __syncthreads();
  float s2 = 0.f;
  for (int i = t; i < N; i += 256) { const float d = src[i] - mean; s2 += d * d; }
  red[t] = s2;
  __syncthreads();
  for (int k = 128; k > 0; k >>= 1) { if (t < k) red[t] += red[t + k]; __syncthreads(); }
  if (t == 0) {
    const float var = red[0] / (float)N;
    const float sc = gamma[o] * rsqrtf(var + 1e-5f);
    scsh[2 * o] = sc;
    scsh[2 * o + 1] = beta[o] - mean * sc;
  }
}

// ---------------------------------------------------------------------------
// Build site matrices (levels 2,3, final): mats[p][s-1][b][ij] (bf16) for s>=1,
// v0[p][b][j] for s==0. BN normalize applied during gather via scsh.
// ---------------------------------------------------------------------------
template <int LEVEL>
__global__ __launch_bounds__(512) void k_build(const float* __restrict__ yraw,
                                               const float* __restrict__ cores,
                                               u16* __restrict__ mats,
                                               float* __restrict__ v0,
                                               const float* __restrict__ scsh) {
  constexpr int S = (LEVEL == 0) ? 16 : 4;
  constexpr int NQ = (LEVEL == 2) ? 2 : 4;
  constexpr int NC = 1024 / NQ;
  constexpr int NTW = NC / 32;
  __shared__ float phi_s[64 * 64];
  const int bid = blockIdx.x;
  const int p = bid / (S * NQ);
  const int rs = bid % (S * NQ);
  const int s = rs / NQ, nq = rs % NQ;
  if (s == 0 && nq != 0) return;   // block-uniform early exit
  const int t = threadIdx.x;
  const int w = t >> 6, lane = t & 63;
  const int g = lane >> 4, l15 = lane & 15;
  for (int i = t; i < 2048; i += 512) {
    const int f = i >> 6, b = i & 63;
    int src;
    if (LEVEL == 2) {
      const int u = (s >> 1) * 8 + (p >> 3), vv = (s & 1) * 8 + (p & 7);
      src = (f * 256 + u * 16 + vv) * 64 + b;
    } else if (LEVEL == 3) {
      const int u = (s >> 1) * 4 + (p >> 2), vv = (s & 1) * 4 + (p & 3);
      src = (f * 64 + u * 8 + vv) * 64 + b;
    } else {
      src = (f * 16 + s) * 64 + b;
    }
    const float val = fmaf(yraw[src], scsh[2 * f], scsh[2 * f + 1]);
    phi_s[f * 64 + b] = val;
    phi_s[(f + 32) * 64 + b] = 1.0f - val;
  }
  __syncthreads();
  const float* Cb = cores + (p * S + s) * 65536;
  const int m = w & 3, nh = w >> 2;
  const int rowb = m * 16 + l15;
  float av[8];
#pragma unroll
  for (int e = 0; e < 8; ++e) av[e] = phi_s[(g * 8 + e) * 64 + rowb];
  const u32x4 afr0 = mk8(av);
#pragma unroll
  for (int e = 0; e < 8; ++e) av[e] = phi_s[(32 + g * 8 + e) * 64 + rowb];
  const u32x4 afr1 = mk8(av);
  if (s == 0) {
    const int col = nh * 16 + l15;   // j in [0,32)
    f32x4 acc = {0.f, 0.f, 0.f, 0.f};
    float bv[8];
#pragma unroll
    for (int e = 0; e < 8; ++e) bv[e] = Cb[(g * 8 + e) * 1024 + col];  // C[f][0][j]
    mfma16(acc, afr0, mk8(bv));
#pragma unroll
    for (int e = 0; e < 8; ++e) bv[e] = Cb[(32 + g * 8 + e) * 1024 + col];
    mfma16(acc, afr1, mk8(bv));
#pragma unroll
    for (int r = 0; r < 4; ++r)
      v0[(p * 64 + m * 16 + g * 4 + r) * 32 + col] = acc[r];
  } else {
#pragma unroll 4
    for (int nt = 0; nt < NTW; ++nt) {
      const int col = nq * NC + (nh * NTW + nt) * 16 + l15;   // ij
      f32x4 acc = {0.f, 0.f, 0.f, 0.f};
      float bv[8];
#pragma unroll
      for (int e = 0; e < 8; ++e) bv[e] = Cb[(g * 8 + e) * 1024 + col];
      mfma16(acc, afr0, mk8(bv));
#pragma unroll
      for (int e = 0; e < 8; ++e) bv[e] = Cb[(32 + g * 8 + e) * 1024 + col];
      mfma16(acc, afr1, mk8(bv));
      u16* mp = mats + (((size_t)p * (S - 1) + (s - 1)) * 64 + m * 16 + g * 4) * 1024 + col;
#pragma unroll
      for (int r = 0; r < 4; ++r) mp[r * 1024] = (u16)f2bf(acc[r]);
    }
  }
}

// ---------------------------------------------------------------------------
// Chain (levels 2,3): v0 -> xM1 xM2 xM3 -> label -> yraw[o][P][b]. Wave per b.
// ---------------------------------------------------------------------------
template <int LEVEL>
__global__ __launch_bounds__(256) void k_chain(const float* __restrict__ v0,
                                               const u16* __restrict__ mats,
                                               const float* __restrict__ label,
                                               float* __restrict__ yraw) {
  constexpr int P = (LEVEL == 2) ? 64 : 16;
  __shared__ float lab_s[1024];   // [j][o]
  const int p = blockIdx.x >> 4, bq = blockIdx.x & 15;
  const int t = threadIdx.x, w = t >> 6, lane = t & 63;
  for (int i = t; i < 1024; i += 256)
    lab_s[(i & 31) * 32 + (i >> 5)] = label[(p * 1024 + i) * 32];
  __syncthreads();
  const int b = bq * 4 + w, j = lane & 31;
  float v = v0[(p * 64 + b) * 32 + j];
#pragma unroll
  for (int s1 = 0; s1 < 3; ++s1) {
    const u16* M = mats + (((size_t)p * 3 + s1) * 64 + b) * 1024;
    float acc = 0.f;
#pragma unroll
    for (int i = 0; i < 32; ++i)
      acc += __shfl(v, i, 64) * bfu2f(M[i * 32 + j]);
    v = acc;
  }
  float out = 0.f;
#pragma unroll
  for (int jj = 0; jj < 32; ++jj)
    out += __shfl(v, jj, 64) * lab_s[jj * 32 + j];
  if (lane < 32) yraw[(j * P + p) * 64 + b] = out;
}

// ---------------------------------------------------------------------------
// Final chain: 15 site matrices then labelF dot. Wave per b.
// ---------------------------------------------------------------------------
__global__ __launch_bounds__(256) void k_chainF(const float* __restrict__ v0,
                                                const u16* __restrict__ mats,
                                                const float* __restrict__ labelF,
                                                float* __restrict__ out) {
  const int t = threadIdx.x, w = t >> 6, lane = t & 63;
  const int b = blockIdx.x * 4 + w, j = lane & 31;
  float v = v0[b * 32 + j];
  for (int s1 = 0; s1 < 15; ++s1) {
    const u16* M = mats + ((size_t)s1 * 64 + b) * 1024;
    float acc = 0.f;
#pragma unroll
    for (int i = 0; i < 32; ++i)
      acc += __shfl(v, i, 64) * bfu2f(M[i * 32 + j]);
    v = acc;
  }
  float r = v * labelF[j * 32];
#pragma unroll
  for (int off = 16; off > 0; off >>= 1) r += __shfl_xor(r, off, 64);
  if (lane == 0) out[b] = r;
}

// ---------------------------------------------------------------------------
extern "C" void kernel_launch(void* const* d_in, const int* in_sizes, int n_in,
                              void* d_out, int out_size, void* d_ws, size_t ws_size,
                              hipStream_t stream) {
  (void)in_sizes; (void)n_in; (void)out_size; (void)ws_size;
  const float* x      = (const float*)d_in[0];
  const float* cores1 = (const float*)d_in[1];
  const float* label1 = (const float*)d_in[2];
  const float* g1     = (const float*)d_in[3];
  const float* b1     = (const float*)d_in[4];
  const float* cores2 = (const float*)d_in[5];
  const float* label2 = (const float*)d_in[6];
  const float* g2     = (const float*)d_in[7];
  const float* b2     = (const float*)d_in[8];
  const float* cores3 = (const float*)d_in[9];
  const float* label3 = (const float*)d_in[10];
  const float* g3     = (const float*)d_in[11];
  const float* b3     = (const float*)d_in[12];
  const float* coresF = (const float*)d_in[13];
  const float* labelF = (const float*)d_in[14];

  char* wsb = (char*)d_ws;
  size_t off = 0;
  auto alloc = [&](size_t bytes) -> char* {
    char* r = wsb + off;
    off += (bytes + 255) & ~(size_t)255;
    return r;
  };
  // phi1 (gather1->level1) and mats2 (build2->chain2) alias (disjoint lifetimes, 24MB)
  char* region0 = alloc(6291456ull * 4);
  float* phi1  = (float*)region0;                 // [256][4][96][64]
  u16*   mats2 = (u16*)region0;                   // [64][3][64][1024]
  float* y1raw = (float*)alloc(524288ull * 4);    // [32][256][64]
  float* v02   = (float*)alloc(131072ull * 4);    // [64][64][32]
  float* y2raw = (float*)alloc(131072ull * 4);    // [32][64][64]
  float* v03   = (float*)alloc(32768ull * 4);     // [16][64][32]
  u16*   mats3 = (u16*)  alloc(3145728ull * 2);   // [16][3][64][1024]
  float* y3raw = (float*)alloc(32768ull * 4);     // [32][16][64]
  float* v0F   = (float*)alloc(2048ull * 4);      // [64][32]
  u16*   matsF = (u16*)  alloc(983040ull * 2);    // [15][64][1024]
  float* scsh1 = (float*)alloc(64 * 4);
  float* scsh2 = (float*)alloc(64 * 4);
  float* scsh3 = (float*)alloc(64 * 4);

  k_gather1<<<768, 256, 0, stream>>>(x, phi1);
  k_level1<<<256, 512, 0, stream>>>(phi1, cores1, label1, y1raw);
  k_bnstats<<<32, 256, 0, stream>>>(y1raw, g1, b1, scsh1, 256);
  k_build<2><<<512, 512, 0, stream>>>(y1raw, cores2, mats2, v02, scsh1);
  k_chain<2><<<1024, 256, 0, stream>>>(v02, mats2, label2, y2raw);
  k_bnstats<<<32, 256, 0, stream>>>(y2raw, g2, b2, scsh2, 64);
  k_build<3><<<256, 512, 0, stream>>>(y2raw, cores3, mats3, v03, scsh2);
  k_chain<3><<<256, 256, 0, stream>>>(v03, mats3, label3, y3raw);
  k_bnstats<<<32, 256, 0, stream>>>(y3raw, g3, b3, scsh3, 16);
  k_build<0><<<64, 512, 0, stream>>>(y3raw, coresF, matsF, v0F, scsh3);
  k_chainF<<<16, 256, 0, stream>>>(v0F, matsF, labelF, (float*)d_out);
}

// Round 6
// 262.538 us; speedup vs baseline: 1.3440x; 1.0630x over previous
//
#include <hip/hip_runtime.h>

typedef unsigned int u32;
typedef unsigned short u16;
typedef float f32x4 __attribute__((ext_vector_type(4)));
typedef u32 u32x4 __attribute__((ext_vector_type(4)));
typedef short s16x8 __attribute__((ext_vector_type(8)));

__device__ __forceinline__ u32 f2bf(float f) {
  u32 x = __builtin_bit_cast(u32, f);
  return (x + 0x7FFFu + ((x >> 16) & 1u)) >> 16;   // RNE f32 -> bf16 bits
}
__device__ __forceinline__ float bfu2f(u16 u) {
  u32 x = ((u32)u) << 16;
  return __builtin_bit_cast(float, x);
}
__device__ __forceinline__ u32 cvtpk(float lo, float hi) {
  u32 r;
  asm("v_cvt_pk_bf16_f32 %0, %1, %2" : "=v"(r) : "v"(lo), "v"(hi));
  return r;
}
__device__ __forceinline__ u32x4 mk8(const float* v) {
  u32x4 u;
  u.x = cvtpk(v[0], v[1]); u.y = cvtpk(v[2], v[3]);
  u.z = cvtpk(v[4], v[5]); u.w = cvtpk(v[6], v[7]);
  return u;
}
// D = A*B + D, 16x16x32 bf16 builtin. D: n=lane&15, m=(lane>>4)*4+r.
__device__ __forceinline__ void mfma16(f32x4& acc, u32x4 a, u32x4 b) {
  acc = __builtin_amdgcn_mfma_f32_16x16x32_bf16(
      __builtin_bit_cast(s16x8, a), __builtin_bit_cast(s16x8, b), acc, 0, 0, 0);
}

// ---------------------------------------------------------------------------
// K0 (R3-proven verbatim): gather x into phi1[p][s][f][b], f in [0,96): [x,1-x]
// ---------------------------------------------------------------------------
__global__ __launch_bounds__(256) void k_gather1(const float* __restrict__ x,
                                                 float* __restrict__ phi1) {
  __shared__ float tile[64][65];
  const int t = threadIdx.x;
  const int base = blockIdx.x * 64;
  const int lb = t & 63;
  {
    const int flat = base + lb;
    const int c = flat >> 14;
    const int r1 = flat & 16383;
    const int h1 = r1 >> 12;
    const int r2 = r1 & 4095;
    const int w1 = r2 >> 10;
    const int r3 = r2 & 1023;
    const int h2 = r3 >> 5;
    const int w2 = r3 & 31;
    const int xoff = c * 16384 + h1 * 4096 + h2 * 128 + w1 * 32 + w2;
    for (int b = t >> 6; b < 64; b += 4)
      tile[lb][b] = x[b * 49152 + xoff];
  }
  __syncthreads();
  for (int q = t >> 6; q < 64; q += 4) {
    const int flat = base + q;
    const int a = flat / 1536;
    const int rem = flat % 1536;
    const int e = rem / 48, gg = rem % 48;
    const int e1 = e >> 4, e2 = e & 15, g1 = gg >> 4, g2 = gg & 15;
    const int tt = a * 6 + e1 * 3 + g1;
    const int F = tt >> 2, Sx = tt & 3, Pp = e2 * 16 + g2;
    const float val = tile[q][lb];
    const int idx = ((Pp * 4 + Sx) * 96 + F) * 64 + lb;
    phi1[idx] = val;
    phi1[idx + 3072] = 1.0f - val;   // f+48
  }
}

// ---------------------------------------------------------------------------
// K1 (R3-proven verbatim): level-1 fused vector-chain. One WG per patch p.
// Wave (jm=w&1, fq=w>>1): private 24-f slice, row-half jm, all 4 b col-blocks.
// 6-slot fo/fi prefetch ring. Partials reduced via padded LDS per site.
// ---------------------------------------------------------------------------
__global__ __launch_bounds__(512) void k_level1(const float* __restrict__ phi1,
                                                const float* __restrict__ cores1,
                                                const float* __restrict__ label1,
                                                float* __restrict__ y1raw) {
  __shared__ float phi_s[96 * 64];          // 24 KB
  __shared__ float v_s[64 * 33];            // 8.4 KB
  __shared__ float red_s[8 * 4 * 16 * 17];  // 34.8 KB
  __shared__ float lab_s[1024];             // 4 KB
  const int p = blockIdx.x, t = threadIdx.x;
  const int w = t >> 6, lane = t & 63, g = lane >> 4, l15 = lane & 15;
  const int jm = w & 1, fq = w >> 1;
  const float* phip = phi1 + p * 24576;
  const float* Cp = cores1 + p * 393216;

  // stage phi(site 0)
  {
    const float4* s4 = (const float4*)phip;
    float4* d4 = (float4*)phi_s;
#pragma unroll
    for (int k = 0; k < 3; ++k) d4[t + k * 512] = s4[t + k * 512];
  }
  __syncthreads();
  // site 0: v[b,j] = sum_f phi[b,f] * C[p,0,f,0,j]
  {
    const int rowj = jm * 16 + l15, colb = fq * 16 + l15;
    f32x4 acc = {0.f, 0.f, 0.f, 0.f};
    const float* A0 = Cp + rowj;
#pragma unroll
    for (int ks = 0; ks < 3; ++ks) {
      float av[8], bv[8];
#pragma unroll
      for (int e = 0; e < 8; ++e) {
        const int f = ks * 32 + g * 8 + e;
        av[e] = A0[f * 1024];
        bv[e] = phi_s[f * 64 + colb];
      }
      mfma16(acc, mk8(av), mk8(bv));
    }
#pragma unroll
    for (int r = 0; r < 4; ++r) v_s[colb * 33 + jm * 16 + g * 4 + r] = acc[r];
  }
  // sites 1..3
  for (int s = 1; s < 4; ++s) {
    __syncthreads();   // v_s complete; phi_s free
    float v8[4][8];
#pragma unroll
    for (int n = 0; n < 4; ++n)
#pragma unroll
      for (int e = 0; e < 8; ++e)
        v8[n][e] = v_s[(n * 16 + l15) * 33 + g * 8 + e];
    {
      const float4* s4 = (const float4*)(phip + s * 6144);
      float4* d4 = (float4*)phi_s;
#pragma unroll
      for (int k = 0; k < 3; ++k) d4[t + k * 512] = s4[t + k * 512];
    }
    // A(f,e) = As[f*1024 + e*32] = C[p][s][fq*24+f][i=g*8+e][j=jm*16+l15]
    const float* As = Cp + s * 98304 + fq * 24576 + g * 256 + jm * 16 + l15;
    float pf[6][8];
#pragma unroll
    for (int fi = 0; fi < 6; ++fi)
#pragma unroll
      for (int e = 0; e < 8; ++e) pf[fi][e] = As[fi * 1024 + e * 32];
    __syncthreads();   // phi ready
    f32x4 acc[4];
#pragma unroll
    for (int n = 0; n < 4; ++n) acc[n] = (f32x4){0.f, 0.f, 0.f, 0.f};
#pragma unroll
    for (int fo = 0; fo < 4; ++fo) {
#pragma unroll
      for (int fi = 0; fi < 6; ++fi) {
        const int f = fo * 6 + fi;
        const u32x4 afr = mk8(pf[fi]);
        if (f + 6 < 24) {
#pragma unroll
          for (int e = 0; e < 8; ++e) pf[fi][e] = As[(f + 6) * 1024 + e * 32];
        }
#pragma unroll
        for (int n = 0; n < 4; ++n) {
          const float phf = phi_s[(fq * 24 + f) * 64 + n * 16 + l15];
          float bv[8];
#pragma unroll
          for (int e = 0; e < 8; ++e) bv[e] = phf * v8[n][e];
          mfma16(acc[n], afr, mk8(bv));
        }
      }
    }
#pragma unroll
    for (int n = 0; n < 4; ++n)
#pragma unroll
      for (int r = 0; r < 4; ++r)
        red_s[((w * 4 + n) * 16 + g * 4 + r) * 17 + l15] = acc[n][r];
    __syncthreads();
    // v[b][j] = sum of 4 fq-partials (waves jj+2*fq)
    for (int i = t; i < 2048; i += 512) {
      const int b = i >> 5, j = i & 31;
      const int n = b >> 4, lb = b & 15, jj = j >> 4, row = j & 15;
      v_s[b * 33 + j] = red_s[(((jj)*4 + n) * 16 + row) * 17 + lb]
                      + red_s[(((jj + 2) * 4 + n) * 16 + row) * 17 + lb]
                      + red_s[(((jj + 4) * 4 + n) * 16 + row) * 17 + lb]
                      + red_s[(((jj + 6) * 4 + n) * 16 + row) * 17 + lb];
    }
  }
  __syncthreads();
  // label contraction: y[b,o] = sum_j v[b,j] * label1[p,o,j,0]
  for (int i = t; i < 1024; i += 512)
    lab_s[(i & 31) * 32 + (i >> 5)] = label1[(p * 1024 + i) * 32];
  __syncthreads();
  {
    const int b = t & 63, og = t >> 6;
    float a[4] = {0.f, 0.f, 0.f, 0.f};
    for (int j = 0; j < 32; ++j) {
      const float vj = v_s[b * 33 + j];
#pragma unroll
      for (int r = 0; r < 4; ++r) a[r] += vj * lab_s[j * 32 + og * 4 + r];
    }
#pragma unroll
    for (int r = 0; r < 4; ++r)
      y1raw[((og * 4 + r) * 256 + p) * 64 + b] = a[r];
  }
}

// ---------------------------------------------------------------------------
// BN stats (R3-proven): per-channel sc/sh to scsh.
// ---------------------------------------------------------------------------
__global__ __launch_bounds__(256) void k_bnstats(const float* __restrict__ yraw,
                                                 const float* __restrict__ gamma,
                                                 const float* __restrict__ beta,
                                                 float* __restrict__ scsh,
                                                 int Pn) {
  __shared__ float red[256];
  const int o = blockIdx.x, t = threadIdx.x;
  const int N = Pn * 64;
  const float* src = yraw + o * N;
  float s = 0.f;
  for (int i = t; i < N; i += 256) s += src[i];
  red[t] = s;
  __syncthreads();
  for (int k = 128; k > 0; k >>= 1) { if (t < k) red[t] += red[t + k]; __syncthreads(); }
  const float mean = red[0] / (float)N;
  __syncthreads();
  float s2 = 0.f;
  for (int i = t; i < N; i += 256) { const float d = src[i] - mean; s2 += d * d; }
  red[t] = s2;
  __syncthreads();
  for (int k = 128; k > 0; k >>= 1) { if (t < k) red[t] += red[t + k]; __syncthreads(); }
  if (t == 0) {
    const float var = red[0] / (float)N;
    const float sc = gamma[o] * rsqrtf(var + 1e-5f);
    scsh[2 * o] = sc;
    scsh[2 * o + 1] = beta[o] - mean * sc;
  }
}

// ---------------------------------------------------------------------------
// Build site matrices (levels 2,3, final). R3-proven body; LEVEL0 NQ=16.
// ---------------------------------------------------------------------------
template <int LEVEL>
__global__ __launch_bounds__(512) void k_build(const float* __restrict__ yraw,
                                               const float* __restrict__ cores,
                                               u16* __restrict__ mats,
                                               float* __restrict__ v0,
                                               const float* __restrict__ scsh) {
  constexpr int S = (LEVEL == 0) ? 16 : 4;
  constexpr int NQ = (LEVEL == 2) ? 2 : ((LEVEL == 3) ? 4 : 16);
  constexpr int NC = 1024 / NQ;
  constexpr int NTW = NC / 32;
  __shared__ float phi_s[64 * 64];
  const int bid = blockIdx.x;
  const int p = bid / (S * NQ);
  const int rs = bid % (S * NQ);
  const int s = rs / NQ, nq = rs % NQ;
  if (s == 0 && nq != 0) return;   // block-uniform early exit
  const int t = threadIdx.x;
  const int w = t >> 6, lane = t & 63;
  const int g = lane >> 4, l15 = lane & 15;
  for (int i = t; i < 2048; i += 512) {
    const int f = i >> 6, b = i & 63;
    int src;
    if (LEVEL == 2) {
      const int u = (s >> 1) * 8 + (p >> 3), vv = (s & 1) * 8 + (p & 7);
      src = (f * 256 + u * 16 + vv) * 64 + b;
    } else if (LEVEL == 3) {
      const int u = (s >> 1) * 4 + (p >> 2), vv = (s & 1) * 4 + (p & 3);
      src = (f * 64 + u * 8 + vv) * 64 + b;
    } else {
      src = (f * 16 + s) * 64 + b;
    }
    const float val = fmaf(yraw[src], scsh[2 * f], scsh[2 * f + 1]);
    phi_s[f * 64 + b] = val;
    phi_s[(f + 32) * 64 + b] = 1.0f - val;
  }
  __syncthreads();
  const float* Cb = cores + (p * S + s) * 65536;
  const int m = w & 3, nh = w >> 2;
  const int rowb = m * 16 + l15;
  float av[8];
#pragma unroll
  for (int e = 0; e < 8; ++e) av[e] = phi_s[(g * 8 + e) * 64 + rowb];
  const u32x4 afr0 = mk8(av);
#pragma unroll
  for (int e = 0; e < 8; ++e) av[e] = phi_s[(32 + g * 8 + e) * 64 + rowb];
  const u32x4 afr1 = mk8(av);
  if (s == 0) {
    const int col = nh * 16 + l15;   // j in [0,32)
    f32x4 acc = {0.f, 0.f, 0.f, 0.f};
    float bv[8];
#pragma unroll
    for (int e = 0; e < 8; ++e) bv[e] = Cb[(g * 8 + e) * 1024 + col];  // C[f][0][j]
    mfma16(acc, afr0, mk8(bv));
#pragma unroll
    for (int e = 0; e < 8; ++e) bv[e] = Cb[(32 + g * 8 + e) * 1024 + col];
    mfma16(acc, afr1, mk8(bv));
#pragma unroll
    for (int r = 0; r < 4; ++r)
      v0[(p * 64 + m * 16 + g * 4 + r) * 32 + col] = acc[r];
  } else {
#pragma unroll 4
    for (int nt = 0; nt < NTW; ++nt) {
      const int col = nq * NC + (nh * NTW + nt) * 16 + l15;   // ij
      f32x4 acc = {0.f, 0.f, 0.f, 0.f};
      float bv[8];
#pragma unroll
      for (int e = 0; e < 8; ++e) bv[e] = Cb[(g * 8 + e) * 1024 + col];
      mfma16(acc, afr0, mk8(bv));
#pragma unroll
      for (int e = 0; e < 8; ++e) bv[e] = Cb[(32 + g * 8 + e) * 1024 + col];
      mfma16(acc, afr1, mk8(bv));
      u16* mp = mats + (((size_t)p * (S - 1) + (s - 1)) * 64 + m * 16 + g * 4) * 1024 + col;
#pragma unroll
      for (int r = 0; r < 4; ++r) mp[r * 1024] = (u16)f2bf(acc[r]);
    }
  }
}

// ---------------------------------------------------------------------------
// Chain (levels 2,3): v0 -> xM1 xM2 xM3 -> label -> yraw[o][P][b].
// LEVEL2: 256 blocks, wave handles 4 b's. LEVEL3: 256 blocks, wave handles 1 b.
// ---------------------------------------------------------------------------
template <int LEVEL>
__global__ __launch_bounds__(256) void k_chain(const float* __restrict__ v0,
                                               const u16* __restrict__ mats,
                                               const float* __restrict__ label,
                                               float* __restrict__ yraw) {
  constexpr int P = (LEVEL == 2) ? 64 : 16;
  constexpr int NB = (LEVEL == 2) ? 4 : 1;   // b's per wave
  __shared__ float lab_s[1024];   // [j][o]
  const int t = threadIdx.x, w = t >> 6, lane = t & 63;
  int p, b0;
  if (LEVEL == 2) { p = blockIdx.x >> 2; b0 = (blockIdx.x & 3) * 16 + w * 4; }
  else            { p = blockIdx.x >> 4; b0 = (blockIdx.x & 15) * 4 + w; }
  for (int i = t; i < 1024; i += 256)
    lab_s[(i & 31) * 32 + (i >> 5)] = label[(p * 1024 + i) * 32];
  __syncthreads();
  const int j = lane & 31;
#pragma unroll
  for (int bi = 0; bi < NB; ++bi) {
    const int b = b0 + bi;
    float v = v0[(p * 64 + b) * 32 + j];
#pragma unroll
    for (int s1 = 0; s1 < 3; ++s1) {
      const u16* M = mats + (((size_t)p * 3 + s1) * 64 + b) * 1024;
      float acc = 0.f;
#pragma unroll
      for (int i = 0; i < 32; ++i)
        acc += __shfl(v, i, 64) * bfu2f(M[i * 32 + j]);
      v = acc;
    }
    float out = 0.f;
#pragma unroll
    for (int jj = 0; jj < 32; ++jj)
      out += __shfl(v, jj, 64) * lab_s[jj * 32 + j];
    if (lane < 32) yraw[(j * P + p) * 64 + b] = out;
  }
}

// ---------------------------------------------------------------------------
// Final chain: 15 site matrices then labelF dot. One wave per block (per b).
// ---------------------------------------------------------------------------
__global__ __launch_bounds__(64) void k_chainF(const float* __restrict__ v0,
                                               const u16* __restrict__ mats,
                                               const float* __restrict__ labelF,
                                               float* __restrict__ out) {
  const int lane = threadIdx.x, b = blockIdx.x, j = lane & 31;
  float v = v0[b * 32 + j];
  for (int s1 = 0; s1 < 15; ++s1) {
    const u16* M = mats + ((size_t)s1 * 64 + b) * 1024;
    float acc = 0.f;
#pragma unroll
    for (int i = 0; i < 32; ++i)
      acc += __shfl(v, i, 64) * bfu2f(M[i * 32 + j]);
    v = acc;
  }
  float r = v * labelF[j * 32];
#pragma unroll
  for (int off = 16; off > 0; off >>= 1) r += __shfl_xor(r, off, 64);
  if (lane == 0) out[b] = r;
}

// ---------------------------------------------------------------------------
extern "C" void kernel_launch(void* const* d_in, const int* in_sizes, int n_in,
                              void* d_out, int out_size, void* d_ws, size_t ws_size,
                              hipStream_t stream) {
  (void)in_sizes; (void)n_in; (void)out_size; (void)ws_size;
  const float* x      = (const float*)d_in[0];
  const float* cores1 = (const float*)d_in[1];
  const float* label1 = (const float*)d_in[2];
  const float* g1     = (const float*)d_in[3];
  const float* b1     = (const float*)d_in[4];
  const float* cores2 = (const float*)d_in[5];
  const float* label2 = (const float*)d_in[6];
  const float* g2     = (const float*)d_in[7];
  const float* b2     = (const float*)d_in[8];
  const float* cores3 = (const float*)d_in[9];
  const float* label3 = (const float*)d_in[10];
  const float* g3     = (const float*)d_in[11];
  const float* b3     = (const float*)d_in[12];
  const float* coresF = (const float*)d_in[13];
  const float* labelF = (const float*)d_in[14];

  char* wsb = (char*)d_ws;
  size_t off = 0;
  auto alloc = [&](size_t bytes) -> char* {
    char* r = wsb + off;
    off += (bytes + 255) & ~(size_t)255;
    return r;
  };
  // phi1 (gather1->level1, 24MB) and mats2 (build2->chain2, 24MB) alias
  char* region0 = alloc(6291456ull * 4);          // 24 MB
  float* phi1  = (float*)region0;                 // [256][4][96][64]
  u16*   mats2 = (u16*)region0;                   // [64][3][64][1024]
  float* y1raw = (float*)alloc(524288ull * 4);    // [32][256][64]
  float* v02   = (float*)alloc(131072ull * 4);    // [64][64][32]
  float* y2raw = (float*)alloc(131072ull * 4);    // [32][64][64]
  float* v03   = (float*)alloc(32768ull * 4);     // [16][64][32]
  u16*   mats3 = (u16*)  alloc(3145728ull * 2);   // [16][3][64][1024]
  float* y3raw = (float*)alloc(32768ull * 4);     // [32][16][64]
  float* v0F   = (float*)alloc(2048ull * 4);      // [64][32]
  u16*   matsF = (u16*)  alloc(983040ull * 2);    // [15][64][1024]
  float* scsh1 = (float*)alloc(64 * 4);
  float* scsh2 = (float*)alloc(64 * 4);
  float* scsh3 = (float*)alloc(64 * 4);

  k_gather1<<<768, 256, 0, stream>>>(x, phi1);
  k_level1<<<256, 512, 0, stream>>>(phi1, cores1, label1, y1raw);
  k_bnstats<<<32, 256, 0, stream>>>(y1raw, g1, b1, scsh1, 256);
  k_build<2><<<512, 512, 0, stream>>>(y1raw, cores2, mats2, v02, scsh1);
  k_chain<2><<<256, 256, 0, stream>>>(v02, mats2, label2, y2raw);
  k_bnstats<<<32, 256, 0, stream>>>(y2raw, g2, b2, scsh2, 64);
  k_build<3><<<256, 512, 0, stream>>>(y2raw, cores3, mats3, v03, scsh2);
  k_chain<3><<<256, 256, 0, stream>>>(v03, mats3, label3, y3raw);
  k_bnstats<<<32, 256, 0, stream>>>(y3raw, g3, b3, scsh3, 16);
  k_build<0><<<256, 512, 0, stream>>>(y3raw, coresF, matsF, v0F, scsh3);
  k_chainF<<<64, 64, 0, stream>>>(v0F, matsF, labelF, (float*)d_out);
}